// Round 5
// baseline (282.291 us; speedup 1.0000x reference)
//
#include <hip/hip_runtime.h>

// B=8, N=32, T=64, D=128, E=4, H=32, BT=512
// R14: spill-proof + 2 blocks/CU. R13 post-mortem: traffic collapsed to 306MB
// as predicted but BW use fell to 1.6TB/s; VGPR_Count=256 (cap) + 168MB
// phantom WRITE = spills; 1 wave/SIMD exposed every latency. Phantom-WRITE
// vs VGPR anti-correlation across R11/R12/R13 (84->316MB, 128->256MB,
// 256->168MB) indicts scratch. Fixes:
//  - LDS 150.5->52KB (no WL weight stage; weights L2-resident: per-XCD
//    streaming data ~4.5MB total, no workspace churn unlike R9).
//  - grid 512, 1 bt/block, launch_bounds(256,2) -> 2 blocks/CU, 2 waves/SIMD.
//  - no thf prefetch (Theta frags loaded inside P7, transient 16 regs);
//    no 2-bt unroll. Peak live ~115 regs vs 256 budget -> no spill possible.
// All phase math verbatim from R13 (absmax 0.03125 preserved).

typedef __bf16 bf16x8 __attribute__((ext_vector_type(8)));
typedef float  f32x4  __attribute__((ext_vector_type(4)));

static __device__ __forceinline__ unsigned short f2bf(float f) {
    unsigned u = __float_as_uint(f);
    u += 0x7fffu + ((u >> 16) & 1u);        // RNE
    return (unsigned short)(u >> 16);
}
static __device__ __forceinline__ float bf2f(unsigned short u) {
    return __uint_as_float(((unsigned)u) << 16);
}
static __device__ __forceinline__ unsigned pack2(float a, float b) {
    return (unsigned)f2bf(a) | ((unsigned)f2bf(b) << 16);
}

// ---------------------------------------------------------------------------
// Wfrag (16B chunks): [0,2048) Wq | [2048,4096) Wk | [4096,6144) Wv |
// [6144,8192) Theta | chunk 8192+: Cq=W1q@Wq (512), chunk 8704+: Ck=W1k@Wk (512).
// B-frag chunk (nt*4+ks)*64+lane holds B[k=j][n]: n = nt*16+(lane&15),
// j = ks*32+(lane>>4)*8 + (0..7).
// ---------------------------------------------------------------------------

__global__ __launch_bounds__(256) void k0_prep(
    const float* __restrict__ Wq, const float* __restrict__ Wk,
    const float* __restrict__ Wv, const float* __restrict__ Theta,
    const float* __restrict__ W1, unsigned short* __restrict__ Wfrag)
{
    const int tid = threadIdx.x;
    if (blockIdx.x < 32) {
        int gid = blockIdx.x * 256 + tid;      // 0..8191
        int g = gid >> 11, c = gid & 2047;
        int ntk = c >> 6, lane = c & 63;
        int i = (ntk >> 2) * 16 + (lane & 15);
        int j = (ntk & 3) * 32 + (lane >> 4) * 8;
        const float* src = (g == 0 ? Wq : g == 1 ? Wk : g == 2 ? Wv : Theta) + (size_t)i * 128 + j;
        float4 a = *(const float4*)(src);
        float4 b = *(const float4*)(src + 4);
        uint4 pk;
        pk.x = pack2(a.x, a.y); pk.y = pack2(a.z, a.w);
        pk.z = pack2(b.x, b.y); pk.w = pack2(b.z, b.w);
        *(uint4*)(Wfrag + (size_t)gid * 8) = pk;
    } else {
        // compose Cq = W1q@Wq, Ck = W1k@Wk
        int b2 = blockIdx.x - 32;              // 0..31
        int mat = b2 & 1;
        int hbase = (b2 >> 1) * 2;
        int hl = tid >> 7, col = tid & 127;
        int h = hbase + hl;
        const float* Wsel = mat ? Wk : Wq;
        const float* w1r = W1 + (size_t)h * 260 + mat * 128;
        float acc = 0.f;
        for (int i = 0; i < 128; ++i)
            acc = fmaf(w1r[i], Wsel[(size_t)i * 128 + col], acc);
        int nt = h >> 4;
        unsigned base = 65536u + (unsigned)mat * 4096u;   // shorts
        int lane = (h & 15) | (((col >> 3) & 3) << 4);
        int ks = col >> 5, vj = col & 7;
        Wfrag[base + (unsigned)((nt * 4 + ks) * 64 + lane) * 8 + vj] = f2bf(acc);
    }
}

// ===== fully fused: grid 512 (1 bt/block), 256 threads, 2 blocks/CU =========
// Arena (52224 B):
//  Qs[32][132] f32 @0        (Zfrag alias pre-proj, ThOut alias post-P7)
//  Ks[32][132] f32 @16896    (Sfrag alias post-P3)
//  Vs[32][136] bf16 @33792 | Lg[32][36] f32 @42496
//  hqL[32][34] bf16 @47104 | hkL[32][34] bf16 @49280
//  W1e_s @51456 | W2_s @51968 | maskrow @52096
__global__ __launch_bounds__(256, 2)
void gnn_all(const float* __restrict__ x, const float* __restrict__ edge,
             const float* __restrict__ A_prior, const unsigned char* __restrict__ pad_mask,
             const unsigned short* __restrict__ Wfrag, const float* __restrict__ Wfuse,
             const float* __restrict__ W1, const float* __restrict__ b1,
             const float* __restrict__ W2, const float* __restrict__ b2,
             const float* __restrict__ gma, const float* __restrict__ bta,
             const float* __restrict__ physw, const float* __restrict__ priorw,
             float* __restrict__ out)
{
    __shared__ __align__(16) unsigned char arena[52224];
    float*          Qs    = (float*)arena;
    unsigned short* Zfrag = (unsigned short*)arena;           // pre-projection
    float*          ThOut = Qs;                               // post-P7, stride 132
    float*          Ks    = (float*)(arena + 16896);
    unsigned short* Sfrag = (unsigned short*)(arena + 16896); // post-P3
    unsigned short* Vs    = (unsigned short*)(arena + 33792); // [32][136]
    float*          Lg    = (float*)(arena + 42496);          // [32][36]
    unsigned short* hqL   = (unsigned short*)(arena + 47104);
    unsigned short* hkL   = (unsigned short*)(arena + 49280);
    float4*         W1e_s = (float4*)(arena + 51456);
    float*          W2_s  = (float*)(arena + 51968);
    float*          maskrow = (float*)(arena + 52096);

    const int tid = threadIdx.x;
    const int bt  = blockIdx.x;
    const int b_  = bt >> 6, t_ = bt & 63;

    const float pw  = physw[0];
    const float rw_ = priorw[0];
    const float b2v = b2[0];
    const float wf0 = Wfuse[0], wf1 = Wfuse[1], wf2 = Wfuse[2],
                wf3 = Wfuse[3], wf4 = Wfuse[4];

    const int wv = tid >> 6, lane = tid & 63;
    const int quad = lane >> 4, col0 = lane & 15;
    const float b1lo = b1[col0], b1hi = b1[16 + col0];
    const int d0p = (tid & 31) * 4, ngp = tid >> 5;           // P6/P8 mapping
    const float4 g4  = *(const float4*)(gma + d0p);
    const float4 be4 = *(const float4*)(bta + d0p);

    // ---- early edge/prior loads (cold HBM; consumed in P3, hidden under
    //      projection); prior folded at arrival: 20 regs total ----
    const int mp = tid & 15, npg = tid >> 4;
    const int n0 = npg * 2, mA = mp, mB = mp + 16;
    float4 e4[2][2];
    float  prv[2][2];
#pragma unroll
    for (int r = 0; r < 2; ++r)
#pragma unroll
        for (int c = 0; c < 2; ++c) {
            int m = c ? mB : mA;
            e4[r][c] = *(const float4*)(edge + (((size_t)bt * 32 + (n0 + r)) * 32 + m) * 4);
            const float* pp = A_prior + (((size_t)bt * 32 + (n0 + r)) * 32 + m) * 5;
            float pr = pp[0]*wf0 + pp[1]*wf1 + pp[2]*wf2 + pp[3]*wf3 + pp[4]*wf4;
            if (!(fabsf(pr) < 1e30f)) pr = 0.f;
            pr = fmaxf(pr, 0.f);
            prv[r][c] = rw_ * __logf(pr + 1e-6f);
        }

    if (tid < 32) {
        W1e_s[tid] = *(const float4*)(W1 + (size_t)tid * 260 + 256);
        W2_s[tid]  = W2[tid];
        maskrow[tid] = pad_mask[b_ * 32 + tid] ? 1.f : 0.f;
    }

    // ---- Z staging: pack x -> bf16 A-frags (512 chunks in Qs region) ----
#pragma unroll
    for (int it2 = 0; it2 < 2; ++it2) {
        int f = tid + 256 * it2;                // chunk 0..511
        int lane9 = f & 63, tk = f >> 6;        // tk 0..7
        int nl = (tk >> 2) * 16 + (lane9 & 15); // token 0..31
        int d  = (tk & 3) * 32 + (lane9 >> 4) * 8;
        const float* xr = x + ((size_t)((b_ * 32 + nl) * 64 + t_)) * 128 + d;
        float4 a = *(const float4*)(xr);
        float4 b = *(const float4*)(xr + 4);
        uint4 pk;
        pk.x = pack2(a.x, a.y); pk.y = pack2(a.z, a.w);
        pk.z = pack2(b.x, b.y); pk.w = pack2(b.z, b.w);
        *(uint4*)(Zfrag + f * 8) = pk;
    }
    __syncthreads();

    // ---- A-frags to regs; barrier before Qs overwrite ----
    bf16x8 avZ[2][4];
#pragma unroll
    for (int tg = 0; tg < 2; ++tg)
#pragma unroll
        for (int ks = 0; ks < 4; ++ks)
            avZ[tg][ks] = *(const bf16x8*)(Zfrag + ((tg * 4 + ks) * 64 + lane) * 8);
    __syncthreads();

    const bf16x8* WfG = (const bf16x8*)Wfrag;    // all weights from L2-global
    const f32x4 zero = {0.f, 0.f, 0.f, 0.f};

    // ---- projection: per wave nt set {wv, wv+4, ..., wv+24} ----
#pragma unroll
    for (int k7 = 0; k7 < 7; ++k7) {
        const int nt = wv + k7 * 4;             // wave-uniform
        const int cb = ((nt < 24) ? nt * 256 : 8192 + (nt - 24) * 256) + lane;
        bf16x8 bw0 = WfG[cb];
        bf16x8 bw1 = WfG[cb + 64];
        bf16x8 bw2 = WfG[cb + 128];
        bf16x8 bw3 = WfG[cb + 192];
        f32x4 acc0 = zero, acc1 = zero;
        acc0 = __builtin_amdgcn_mfma_f32_16x16x32_bf16(avZ[0][0], bw0, acc0, 0, 0, 0);
        acc1 = __builtin_amdgcn_mfma_f32_16x16x32_bf16(avZ[1][0], bw0, acc1, 0, 0, 0);
        acc0 = __builtin_amdgcn_mfma_f32_16x16x32_bf16(avZ[0][1], bw1, acc0, 0, 0, 0);
        acc1 = __builtin_amdgcn_mfma_f32_16x16x32_bf16(avZ[1][1], bw1, acc1, 0, 0, 0);
        acc0 = __builtin_amdgcn_mfma_f32_16x16x32_bf16(avZ[0][2], bw2, acc0, 0, 0, 0);
        acc1 = __builtin_amdgcn_mfma_f32_16x16x32_bf16(avZ[1][2], bw2, acc1, 0, 0, 0);
        acc0 = __builtin_amdgcn_mfma_f32_16x16x32_bf16(avZ[0][3], bw3, acc0, 0, 0, 0);
        acc1 = __builtin_amdgcn_mfma_f32_16x16x32_bf16(avZ[1][3], bw3, acc1, 0, 0, 0);
#pragma unroll
        for (int tg = 0; tg < 2; ++tg) {
            const f32x4 acc = tg ? acc1 : acc0;
            const int tokb = tg * 16 + quad * 4;
#pragma unroll
            for (int reg = 0; reg < 4; ++reg) {
                int tok = tokb + reg;
                float v = acc[reg];
                if (nt < 8)       Qs[tok * 132 + nt * 16 + col0] = v;
                else if (nt < 16) Ks[tok * 132 + (nt - 8) * 16 + col0] = v;
                else if (nt < 24) Vs[tok * 136 + (nt - 16) * 16 + col0] = f2bf(v);
                else if (nt < 26) hqL[tok * 34 + (nt - 24) * 16 + col0] = f2bf(v + (nt == 24 ? b1lo : b1hi));
                else              hkL[tok * 34 + (nt - 26) * 16 + col0] = f2bf(v);
            }
        }
    }
    __syncthreads();

    // ---- P3: logits (fp32 VALU QK^T + phys MLP + prior) -> Lg ----
    {
        const float* qa = Qs + n0 * 132;
        const float* qb = qa + 132;
        const float* ka = Ks + mA * 132;
        const float* kb = Ks + mB * 132;
        float a00 = 0.f, a01 = 0.f, a10 = 0.f, a11 = 0.f;
        for (int j = 0; j < 128; j += 4) {
            float4 kva = *(const float4*)(ka + j);
            float4 kvb = *(const float4*)(kb + j);
            float4 qva = *(const float4*)(qa + j);
            float4 qvb = *(const float4*)(qb + j);
            a00 = fmaf(qva.x, kva.x, fmaf(qva.y, kva.y, fmaf(qva.z, kva.z, fmaf(qva.w, kva.w, a00))));
            a01 = fmaf(qva.x, kvb.x, fmaf(qva.y, kvb.y, fmaf(qva.z, kvb.z, fmaf(qva.w, kvb.w, a01))));
            a10 = fmaf(qvb.x, kva.x, fmaf(qvb.y, kva.y, fmaf(qvb.z, kva.z, fmaf(qvb.w, kva.w, a10))));
            a11 = fmaf(qvb.x, kvb.x, fmaf(qvb.y, kvb.y, fmaf(qvb.z, kvb.z, fmaf(qvb.w, kvb.w, a11))));
        }
        float pacc[2][2] = {{0.f, 0.f}, {0.f, 0.f}};
#pragma unroll
        for (int h = 0; h < 32; ++h) {
            float4 we = W1e_s[h];
            float w2v = W2_s[h];
            float hq0 = bf2f(hqL[n0 * 34 + h]);
            float hq1 = bf2f(hqL[(n0 + 1) * 34 + h]);
            float hkA = bf2f(hkL[mA * 34 + h]);
            float hkB = bf2f(hkL[mB * 34 + h]);
#pragma unroll
            for (int r = 0; r < 2; ++r) {
                float hqv = r ? hq1 : hq0;
#pragma unroll
                for (int c = 0; c < 2; ++c) {
                    float hkv = c ? hkB : hkA;
                    float4 e = e4[r][c];
                    float he = fmaf(e.x, we.x, fmaf(e.y, we.y, fmaf(e.z, we.z, e.w * we.w)));
                    pacc[r][c] = fmaf(fmaxf(hqv + hkv + he, 0.f), w2v, pacc[r][c]);
                }
            }
        }
        float cont[2][2] = {{a00, a01}, {a10, a11}};
#pragma unroll
        for (int r = 0; r < 2; ++r)
#pragma unroll
            for (int c = 0; c < 2; ++c) {
                int n = n0 + r, m = c ? mB : mA;
                float lg = cont[r][c] * 0.08838834764831845f
                         + pw * (pacc[r][c] + b2v) + prv[r][c];
                if (maskrow[n] != 0.f || maskrow[m] != 0.f) lg = -1e9f;
                Lg[n * 36 + m] = lg;
            }
    }
    __syncthreads();

    // ---- P4: wave-parallel softmax (8 lanes per row) ----
    {
        const int n = tid >> 3, q = tid & 7;
        float4 v = *(const float4*)(Lg + n * 36 + q * 4);
        float mx = fmaxf(fmaxf(v.x, v.y), fmaxf(v.z, v.w));
#pragma unroll
        for (int off = 1; off < 8; off <<= 1)
            mx = fmaxf(mx, __shfl_xor(mx, off, 64));
        float ex = __expf(v.x - mx), ey = __expf(v.y - mx),
              ez = __expf(v.z - mx), ew = __expf(v.w - mx);
        float s = (ex + ey) + (ez + ew);
#pragma unroll
        for (int off = 1; off < 8; off <<= 1)
            s += __shfl_xor(s, off, 64);
        float inv = 1.f / s;
        float4 o; o.x = ex * inv; o.y = ey * inv; o.z = ez * inv; o.w = ew * inv;
        *(float4*)(Lg + n * 36 + q * 4) = o;
    }
    __syncthreads();

    const int rg = wv & 1, ch = wv >> 1;

    // ---- P6: spatial = alpha @ V (4 rows/thread) -> Sfrag bf16 A-frags ----
    {
        const int vks = d0p >> 5, vq = (d0p >> 3) & 3, vj = d0p & 7;
        float sa[4][4] = {};
        for (int m = 0; m < 32; m += 4) {
            float alv[4][4];
#pragma unroll
            for (int r = 0; r < 4; ++r) {
                float4 t = *(const float4*)(Lg + (ngp * 4 + r) * 36 + m);
                alv[r][0] = t.x; alv[r][1] = t.y; alv[r][2] = t.z; alv[r][3] = t.w;
            }
#pragma unroll
            for (int mm = 0; mm < 4; ++mm) {
                uint2 vv = *(const uint2*)(Vs + (m + mm) * 136 + d0p);
                float v0 = bf2f((unsigned short)(vv.x & 0xffffu));
                float v1 = bf2f((unsigned short)(vv.x >> 16));
                float v2 = bf2f((unsigned short)(vv.y & 0xffffu));
                float v3 = bf2f((unsigned short)(vv.y >> 16));
#pragma unroll
                for (int r = 0; r < 4; ++r) {
                    float a = alv[r][mm];
                    sa[r][0] = fmaf(a, v0, sa[r][0]); sa[r][1] = fmaf(a, v1, sa[r][1]);
                    sa[r][2] = fmaf(a, v2, sa[r][2]); sa[r][3] = fmaf(a, v3, sa[r][3]);
                }
            }
        }
        // Sfrag aliases Ks (dead after P3)
#pragma unroll
        for (int r = 0; r < 4; ++r) {
            int nloc = ngp * 4 + r;
            int tg = nloc >> 4, nl = nloc & 15;
            unsigned short* sp = Sfrag + ((tg * 4 + vks) * 64 + vq * 16 + nl) * 8 + vj;
            sp[0] = f2bf(sa[r][0]); sp[1] = f2bf(sa[r][1]);
            sp[2] = f2bf(sa[r][2]); sp[3] = f2bf(sa[r][3]);
        }
    }
    __syncthreads();

    // ---- P7: Theta MFMA -> ThOut (alias Qs, stride 132); B-frags loaded
    //      inline per nt (transient 16 regs; L2-hit, hidden by co-block) ----
    {
        f32x4 aT[4] = {zero, zero, zero, zero};
        bf16x8 av0 = *(const bf16x8*)(Sfrag + ((rg * 4 + 0) * 64 + lane) * 8);
        bf16x8 av1 = *(const bf16x8*)(Sfrag + ((rg * 4 + 1) * 64 + lane) * 8);
        bf16x8 av2 = *(const bf16x8*)(Sfrag + ((rg * 4 + 2) * 64 + lane) * 8);
        bf16x8 av3 = *(const bf16x8*)(Sfrag + ((rg * 4 + 3) * 64 + lane) * 8);
#pragma unroll
        for (int nt = 0; nt < 4; ++nt) {
            const int cb = 6144 + ((ch * 4 + nt) * 4) * 64 + lane;
            bf16x8 t0 = WfG[cb];
            bf16x8 t1 = WfG[cb + 64];
            bf16x8 t2 = WfG[cb + 128];
            bf16x8 t3 = WfG[cb + 192];
            aT[nt] = __builtin_amdgcn_mfma_f32_16x16x32_bf16(av0, t0, aT[nt], 0, 0, 0);
            aT[nt] = __builtin_amdgcn_mfma_f32_16x16x32_bf16(av1, t1, aT[nt], 0, 0, 0);
            aT[nt] = __builtin_amdgcn_mfma_f32_16x16x32_bf16(av2, t2, aT[nt], 0, 0, 0);
            aT[nt] = __builtin_amdgcn_mfma_f32_16x16x32_bf16(av3, t3, aT[nt], 0, 0, 0);
        }
#pragma unroll
        for (int nt = 0; nt < 4; ++nt) {
            int colc = ch * 64 + nt * 16 + col0;
#pragma unroll
            for (int reg = 0; reg < 4; ++reg)
                ThOut[(rg * 16 + quad * 4 + reg) * 132 + colc] = aT[nt][reg];
        }
    }
    __syncthreads();

    // ---- P8: y = x + ThOut; LayerNorm; mask; store (4 rows/thread) ----
    {
#pragma unroll
        for (int r = 0; r < 4; ++r) {
            int nloc = ngp * 4 + r;
            const float* xr = x + ((size_t)((b_ * 32 + nloc) * 64 + t_)) * 128 + d0p;
            float4 z  = *(const float4*)(xr);
            float4 th = *(const float4*)(ThOut + nloc * 132 + d0p);
            float y0 = th.x + z.x, y1 = th.y + z.y, y2 = th.z + z.z, y3 = th.w + z.w;
            float s  = (y0 + y1) + (y2 + y3);
            float s2 = (y0*y0 + y1*y1) + (y2*y2 + y3*y3);
#pragma unroll
            for (int off = 1; off < 32; off <<= 1) {
                s  += __shfl_xor(s,  off, 64);
                s2 += __shfl_xor(s2, off, 64);
            }
            float mu   = s * 0.0078125f;
            float var  = s2 * 0.0078125f - mu * mu;
            float rstd = rsqrtf(var + 1e-5f);
            float msk  = (maskrow[nloc] != 0.f) ? 0.f : 1.f;
            float4 o;
            o.x = ((y0 - mu) * rstd * g4.x + be4.x) * msk;
            o.y = ((y1 - mu) * rstd * g4.y + be4.y) * msk;
            o.z = ((y2 - mu) * rstd * g4.z + be4.z) * msk;
            o.w = ((y3 - mu) * rstd * g4.w + be4.w) * msk;
            *(float4*)(out + ((size_t)((b_ * 32 + nloc) * 64 + t_)) * 128 + d0p) = o;
        }
    }
}

// ===========================================================================
extern "C" void kernel_launch(void* const* d_in, const int* in_sizes, int n_in,
                              void* d_out, int out_size, void* d_ws, size_t ws_size,
                              hipStream_t stream) {
    const float* x        = (const float*)d_in[0];
    const float* edge     = (const float*)d_in[1];
    const float* A_prior  = (const float*)d_in[2];
    const unsigned char* pad_mask = (const unsigned char*)d_in[3];
    const float* Wq       = (const float*)d_in[4];
    const float* Wk       = (const float*)d_in[5];
    const float* Wv       = (const float*)d_in[6];
    const float* Theta    = (const float*)d_in[7];
    const float* Wfuse    = (const float*)d_in[8];
    const float* W1       = (const float*)d_in[9];
    const float* b1       = (const float*)d_in[10];
    const float* W2       = (const float*)d_in[11];
    const float* b2       = (const float*)d_in[12];
    const float* gma      = (const float*)d_in[13];
    const float* bta      = (const float*)d_in[14];
    const float* physw    = (const float*)d_in[15];
    const float* priorw   = (const float*)d_in[16];
    float* out = (float*)d_out;

    unsigned short* Wfrag = (unsigned short*)d_ws;   // 147456 B (9216 chunks)

    k0_prep<<<dim3(64), dim3(256), 0, stream>>>(Wq, Wk, Wv, Theta, W1, Wfrag);
    gnn_all<<<dim3(512), dim3(256), 0, stream>>>(
        x, edge, A_prior, pad_mask, Wfrag, Wfuse,
        W1, b1, W2, b2, gma, bta, physw, priorw, out);
}